// Round 8
// baseline (1150.861 us; speedup 1.0000x reference)
//
#include <hip/hip_runtime.h>

#define KDIM 128

__global__ __launch_bounds__(256) void perm_scatter_kernel(const float* __restrict__ x,
                                                           float* __restrict__ out) {
    __shared__ float rows[2][KDIM];

    const int t = threadIdx.x;                       // 0..255
    const int half = t >> 7;                         // which of the 2 rows
    const int j = t & 127;                           // element index within row
    const long long row_id = (long long)blockIdx.x * 2 + half;

    // 256 threads read 256 consecutive floats (2 adjacent rows) — fully coalesced.
    rows[half][j] = x[row_id * KDIM + j];
    __syncthreads();

    const float xj = rows[half][j];
    int rank = 0;
#pragma unroll
    for (int l = 0; l < KDIM; ++l) {
        const float xl = rows[half][l];
        // descending, stable: earlier index wins ties (matches stable argsort(-x))
        rank += (xl > xj) || (xl == xj && l < j);
    }
    // P[row_id, rank, j] = 1  (rank-th largest element lives at column j)
    out[row_id * (long long)(KDIM * KDIM) + (long long)rank * KDIM + j] = 1.0f;
}

extern "C" void kernel_launch(void* const* d_in, const int* in_sizes, int n_in,
                              void* d_out, int out_size, void* d_ws, size_t ws_size,
                              hipStream_t stream) {
    const float* x = (const float*)d_in[0];
    float* out = (float*)d_out;
    const int n_rows = in_sizes[0] / KDIM;           // 16384

    // Zero the whole 1 GiB output via a memset node (graph-capturable),
    // then scatter only the ones.
    hipMemsetAsync(d_out, 0, (size_t)out_size * sizeof(float), stream);
    perm_scatter_kernel<<<n_rows / 2, 256, 0, stream>>>(x, out);
}

// Round 12
// 1058.618 us; speedup vs baseline: 1.0871x; 1.0871x over previous
//
#include <hip/hip_runtime.h>

#define KDIM 128

typedef float f32x4 __attribute__((ext_vector_type(4)));

__global__ __launch_bounds__(256) void perm_onehot_fused(const float* __restrict__ x,
                                                         float* __restrict__ out) {
    __shared__ float row[KDIM];
    __shared__ int col_of[KDIM];

    const int t = threadIdx.x;
    const long long row_id = blockIdx.x;

    // Threads 0-127 load the row (coalesced), compute each element's
    // descending stable rank via LDS-broadcast compares, and build the
    // inverse permutation col_of[rank] = source column.
    if (t < KDIM) row[t] = x[row_id * KDIM + t];
    __syncthreads();

    if (t < KDIM) {
        const float xj = row[t];
        int rank = 0;
#pragma unroll
        for (int l = 0; l < KDIM; ++l) {
            const float xl = row[l];
            // descending, stable: earlier index wins ties (== stable argsort(-x))
            rank += (xl > xj) || (xl == xj && l < t);
        }
        col_of[rank] = t;
    }
    __syncthreads();

    // All 256 threads write the 128x128 one-hot block in one pass:
    // 4096 float4 stores, fully coalesced, nontemporal (streaming 1 GiB,
    // no reuse -> bypass L2 allocation).
    f32x4* outr = (f32x4*)(out + row_id * (long long)(KDIM * KDIM));
#pragma unroll
    for (int k = 0; k < 16; ++k) {
        const int q = t + k * 256;          // linear float4 index in the block
        const int i = q >> 5;               // output row (32 float4 per row)
        const int c = (q & 31) << 2;        // starting column of this float4
        const int oc = col_of[i];
        f32x4 v;
        v.x = (c + 0 == oc) ? 1.0f : 0.0f;
        v.y = (c + 1 == oc) ? 1.0f : 0.0f;
        v.z = (c + 2 == oc) ? 1.0f : 0.0f;
        v.w = (c + 3 == oc) ? 1.0f : 0.0f;
        __builtin_nontemporal_store(v, &outr[q]);
    }
}

extern "C" void kernel_launch(void* const* d_in, const int* in_sizes, int n_in,
                              void* d_out, int out_size, void* d_ws, size_t ws_size,
                              hipStream_t stream) {
    const float* x = (const float*)d_in[0];
    float* out = (float*)d_out;
    const int n_rows = in_sizes[0] / KDIM;   // 16384
    perm_onehot_fused<<<n_rows, 256, 0, stream>>>(x, out);
}